// Round 2
// baseline (428.707 us; speedup 1.0000x reference)
//
#include <hip/hip_runtime.h>

// Correlation layer: out[b, di*9+dj, h, w] = (1/64) * sum_c x1[b,c,h,w] * x2p[b,c,h+di,w+dj]
// x2p = zero-pad-4 of x2. B=8, C=64, H=W=192.
//
// Round-2 design: latency was the round-1 bottleneck (VALUBusy 21%, occ 24%).
//  - Ping-pong LDS double buffer, CK=8 channels/chunk (2 x 28KB = 56KB).
//  - Staging via __builtin_amdgcn_global_load_lds width=16 (async DMA, no VGPR
//    round-trip). Issue chunk k+1 right after the barrier, compute chunk k;
//    the vmcnt(0) drain at the next barrier lands after a full compute phase.
//  - pad=4 == float4 width -> every halo float4 is fully in- or out-of-bounds;
//    OOB lanes load from a zero-filled __device__ page (module globals are
//    zero-initialized, never written).
//  - All DMA batches are whole-wave uniform (x1: waves 0..7; x2: all + waves 0,1).
//
// Block: 576 threads = 9 waves; wave w handles displacement row di=w.
// Lane: 4 consecutive w-pixels, 1 h-row. acc[9 dj][4 px] = 36 VGPRs.

constexpr int MAXD = 4;
constexpr int OD   = 9;
constexpr int ND   = 81;
constexpr int TB_W = 32;
constexpr int TB_H = 8;
constexpr int TWp  = 4;
constexpr int CK   = 8;                   // channels per chunk
constexpr int X2W  = TB_W + 2 * MAXD;     // 40
constexpr int X2H  = TB_H + 2 * MAXD;     // 16
constexpr int NT   = 576;

constexpr int Bc = 8, Cc = 64, Hc = 192, Wc = 192;
constexpr int HW = Hc * Wc;
constexpr int X1SZ = CK * TB_H * TB_W;    // 2048 floats (8KB)
constexpr int X2SZ = CK * X2H * X2W;      // 5120 floats (20KB)
constexpr int NCHUNK = Cc / CK;           // 8

__device__ __attribute__((aligned(16))) float g_zero_page[4];  // zero-init at load

__device__ __forceinline__ void async_cp16(const float* src, float* lds_dst) {
    __builtin_amdgcn_global_load_lds(
        (const __attribute__((address_space(1))) unsigned int*)src,
        (__attribute__((address_space(3))) unsigned int*)lds_dst,
        16, 0, 0);
}

__global__ __launch_bounds__(NT, 5) void corr_kernel(
    const float* __restrict__ x1, const float* __restrict__ x2,
    float* __restrict__ out)
{
    __shared__ float sx1[2][X1SZ];   // 2 x 8KB
    __shared__ float sx2[2][X2SZ];   // 2 x 20KB

    const int tid = threadIdx.x;
    const int g   = tid & 63;
    const int di  = tid >> 6;        // 0..8, wave-uniform
    const int gw4 = (g & 7) * 4;
    const int gh  = g >> 3;

    const int w0 = blockIdx.x * TB_W;
    const int h0 = blockIdx.y * TB_H;
    const int b  = blockIdx.z;

    const float* x1b = x1 + (long)b * Cc * HW;
    const float* x2b = x2 + (long)b * Cc * HW;

    // ---- stage one chunk (channels [c0, c0+CK)) into buffer `buf` via DMA ----
    auto stage_x2_one = [&](int c0, int buf, int idx) {
        // idx in [0, 1280) float4s; layout linear: c*640 + y*40 + x floats
        int c  = idx / 160;              // 160 float4 per channel (16*40/4)
        int r  = idx - c * 160;
        int y  = r / 10;                 // 10 float4 per row
        int xq = r - y * 10;
        int gy = h0 + y - MAXD;
        int gx = w0 + xq * 4 - MAXD;     // multiple of 4; fully in or fully out
        const float* src =
            ((unsigned)gy < (unsigned)Hc && (unsigned)gx < (unsigned)Wc)
                ? (x2b + (long)(c0 + c) * HW + gy * Wc + gx)
                : g_zero_page;
        async_cp16(src, &sx2[buf][idx * 4]);
    };

    auto stage = [&](int c0, int buf) {
        // x1 tile: 2048 floats = 512 float4 -> full waves 0..7, one each
        if (tid < X1SZ / 4) {
            int f = tid * 4;
            int c = f >> 8;              // /(TB_H*TB_W)
            int r = f & 255;
            int y = r >> 5;
            int x = r & 31;
            async_cp16(x1b + (long)(c0 + c) * HW + (h0 + y) * Wc + (w0 + x),
                       &sx1[buf][f]);
        }
        // x2 halo tile: 5120 floats = 1280 float4 = 576 + 576 + 128
        stage_x2_one(c0, buf, tid);
        stage_x2_one(c0, buf, tid + NT);
        if (tid < 1280 - 2 * NT)         // waves 0,1 fully active
            stage_x2_one(c0, buf, tid + 2 * NT);
    };

    float acc[OD][TWp];
#pragma unroll
    for (int dj = 0; dj < OD; ++dj)
#pragma unroll
        for (int p = 0; p < TWp; ++p) acc[dj][p] = 0.f;

    stage(0, 0);  // prefetch chunk 0

    for (int k = 0; k < NCHUNK; ++k) {
        const int cur = k & 1;
        __syncthreads();                 // drains DMA of chunk k + prior reads
        if (k + 1 < NCHUNK)
            stage((k + 1) * CK, cur ^ 1);  // async: overlaps compute below

        // ---- compute chunk k: per channel 4x ds_read_b128 -> 36 FMAs ----
#pragma unroll
        for (int c = 0; c < CK; ++c) {
            float4 a = *(const float4*)(&sx1[cur][c * (TB_H * TB_W) + gh * TB_W + gw4]);
            const float* wr = &sx2[cur][c * (X2H * X2W) + (gh + di) * X2W + gw4];
            float4 b0 = *(const float4*)(wr);
            float4 b1 = *(const float4*)(wr + 4);
            float4 b2 = *(const float4*)(wr + 8);
            float win[12] = {b0.x, b0.y, b0.z, b0.w,
                             b1.x, b1.y, b1.z, b1.w,
                             b2.x, b2.y, b2.z, b2.w};
            float av[4] = {a.x, a.y, a.z, a.w};
#pragma unroll
            for (int dj = 0; dj < OD; ++dj)
#pragma unroll
                for (int p = 0; p < TWp; ++p)
                    acc[dj][p] = fmaf(av[p], win[dj + p], acc[dj][p]);
        }
    }

    // ---- epilogue: 9 float4 stores (mean over C=64) ----
    const float scale = 1.0f / 64.0f;
    float* ob = out + (((long)b * ND + di * OD) * Hc + (h0 + gh)) * Wc + (w0 + gw4);
#pragma unroll
    for (int dj = 0; dj < OD; ++dj) {
        float4 o;
        o.x = acc[dj][0] * scale;
        o.y = acc[dj][1] * scale;
        o.z = acc[dj][2] * scale;
        o.w = acc[dj][3] * scale;
        *(float4*)(ob + (long)dj * HW) = o;
    }
}

extern "C" void kernel_launch(void* const* d_in, const int* in_sizes, int n_in,
                              void* d_out, int out_size, void* d_ws, size_t ws_size,
                              hipStream_t stream) {
    const float* x1 = (const float*)d_in[0];
    const float* x2 = (const float*)d_in[1];
    float* out = (float*)d_out;
    dim3 grid(Wc / TB_W, Hc / TB_H, Bc);  // (6, 24, 8) = 1152 blocks
    corr_kernel<<<grid, NT, 0, stream>>>(x1, x2, out);
}